// Round 4
// baseline (298.045 us; speedup 1.0000x reference)
//
#include <hip/hip_runtime.h>

typedef _Float16 f16;
typedef _Float16 f16x2 __attribute__((ext_vector_type(2)));
typedef _Float16 f16x8 __attribute__((ext_vector_type(8)));
typedef float f32x4 __attribute__((ext_vector_type(4)));

#define I_DIM 320
#define J_DIM 320
#define C_DIM 128
#define H_DIM 4
#define DH 32
#define NROWS (I_DIM * J_DIM)   // 102400

// ---------------- K0: weight prep (f32 -> f16, MFMA B-fragment order) ------
// layout: [w][ks][n][lane][j]; value = W_w[(ks*32+(lane>>4)*8+j)*128 + n*16+(lane&15)]
__global__ __launch_bounds__(256) void prep_kernel(const float* __restrict__ Wq,
                                                   const float* __restrict__ Wk,
                                                   const float* __restrict__ Wv,
                                                   const float* __restrict__ Wg,
                                                   const float* __restrict__ Wo,
                                                   f16* __restrict__ Wfrag) {
    int f = blockIdx.x * 256 + threadIdx.x;           // < 5*16384
    int j = f & 7, lane = (f >> 3) & 63, n = (f >> 9) & 7;
    int ks = (f >> 12) & 3, w = f >> 14;
    int gq = lane >> 4, r16 = lane & 15;
    const float* W = (w == 0) ? Wq : (w == 1) ? Wk : (w == 2) ? Wv : (w == 3) ? Wg : Wo;
    Wfrag[f] = (f16)W[(size_t)(ks * 32 + gq * 8 + j) * 128 + n * 16 + r16];
}

// ---------------- K1: LayerNorm (f32 -> f16) — EXACT round-1 ----------------
__global__ __launch_bounds__(256) void ln_kernel(const float* __restrict__ z,
                                                 const float* __restrict__ scale,
                                                 const float* __restrict__ bias,
                                                 f16* __restrict__ zn) {
    int wave = threadIdx.x >> 6;
    int lane = threadIdx.x & 63;
    int row = blockIdx.x * 4 + wave;
    const float* zr = z + (size_t)row * C_DIM;
    float2 x = *(const float2*)(zr + lane * 2);
    float s = x.x + x.y;
    float sq = x.x * x.x + x.y * x.y;
    #pragma unroll
    for (int o = 32; o; o >>= 1) {
        s  += __shfl_xor(s, o);
        sq += __shfl_xor(sq, o);
    }
    float mu = s * (1.0f / 128.0f);
    float var = sq * (1.0f / 128.0f) - mu * mu;
    float rs = rsqrtf(var + 1e-5f);
    int c0 = lane * 2;
    float y0 = (x.x - mu) * rs * scale[c0] + bias[c0];
    float y1 = (x.y - mu) * rs * scale[c0 + 1] + bias[c0 + 1];
    f16x2 o2 = {(f16)y0, (f16)y1};
    *(f16x2*)(zn + (size_t)row * C_DIM + c0) = o2;
}

// ---------------- K2: fused QKVG projection — round-1 structure, Wfrag B ----
// grid: NROWS/64 blocks, 256 threads. Wave w computes zn@W_w for its 64-row tile.
__global__ __launch_bounds__(256) void proj_kernel(const f16* __restrict__ zn,
                                                   const f16* __restrict__ Wfrag,
                                                   const float* __restrict__ bg,
                                                   f16* __restrict__ q, f16* __restrict__ k,
                                                   f16* __restrict__ v, f16* __restrict__ g) {
    int wave = threadIdx.x >> 6;
    int lane = threadIdx.x & 63;
    int gq = lane >> 4, r16 = lane & 15;
    int row0 = blockIdx.x * 64;

    const f16* wf = Wfrag + wave * 16384;

    f32x4 acc[4][8] = {};
    #pragma unroll
    for (int ks = 0; ks < 4; ++ks) {
        f16x8 a[4];
        #pragma unroll
        for (int m = 0; m < 4; ++m)
            a[m] = *(const f16x8*)(zn + (size_t)(row0 + m * 16 + r16) * C_DIM + ks * 32 + gq * 8);
        #pragma unroll
        for (int n = 0; n < 8; ++n) {
            f16x8 b = *(const f16x8*)(wf + (ks * 8 + n) * 512 + lane * 8);
            #pragma unroll
            for (int m = 0; m < 4; ++m)
                acc[m][n] = __builtin_amdgcn_mfma_f32_16x16x32_f16(a[m], b, acc[m][n], 0, 0, 0);
        }
    }

    f16* outp = (wave == 0) ? q : (wave == 1) ? k : (wave == 2) ? v : g;
    #pragma unroll
    for (int m = 0; m < 4; ++m) {
        #pragma unroll
        for (int n = 0; n < 8; ++n) {
            int col = n * 16 + r16;
            #pragma unroll
            for (int rr = 0; rr < 4; ++rr) {
                int row = row0 + m * 16 + gq * 4 + rr;
                float val = acc[m][n][rr];
                if (wave == 3) val = 1.0f / (1.0f + __expf(-(val + bg[col])));
                outp[(size_t)row * C_DIM + col] = (f16)val;
            }
        }
    }
}

// ---------------- K3: attention per (i,h) — EXACT round-1 ----------------
__global__ __launch_bounds__(256) void attn_kernel(const f16* __restrict__ q,
                                                   const f16* __restrict__ k,
                                                   const f16* __restrict__ v,
                                                   const f16* __restrict__ g,
                                                   const int* __restrict__ z_mask,
                                                   f16* __restrict__ gwa) {
    __shared__ f16 Ksh[320][40];      // padded rows: 80B stride -> 2-way banks only
    __shared__ f16 Vt[32][328];       // V transposed [dh][key], padded
    __shared__ float mb[320];
    __shared__ f16 Psh[4][2][16][40]; // per-wave, double-buffered P chunk

    int h = blockIdx.x & 3;
    int i = blockIdx.x >> 2;
    size_t base = (size_t)i * (J_DIM * C_DIM) + h * DH;

    // stage K and V^T
    for (int t = threadIdx.x; t < 320 * 4; t += 256) {
        int row = t >> 2, c8 = (t & 3) * 8;
        f16x8 kv = *(const f16x8*)(k + base + (size_t)row * C_DIM + c8);
        *(f16x8*)(&Ksh[row][c8]) = kv;
        f16x8 vv = *(const f16x8*)(v + base + (size_t)row * C_DIM + c8);
        #pragma unroll
        for (int j = 0; j < 8; ++j) Vt[c8 + j][row] = vv[j];
    }
    for (int t = threadIdx.x; t < 320; t += 256)
        mb[t] = 1e9f * ((float)z_mask[i * J_DIM + t] - 1.0f);
    __syncthreads();

    int wave = threadIdx.x >> 6;
    int lane = threadIdx.x & 63;
    int gq = lane >> 4, r16 = lane & 15;

    for (int qt = wave; qt < 20; qt += 4) {
        f16x8 qa = *(const f16x8*)(q + base + (size_t)(qt * 16 + r16) * C_DIM + gq * 8);
        f32x4 zero = {};
        f32x4 lg[20];
        #pragma unroll
        for (int kt = 0; kt < 20; ++kt) {
            f16x8 kb = *(const f16x8*)(&Ksh[kt * 16 + r16][gq * 8]);
            lg[kt] = __builtin_amdgcn_mfma_f32_16x16x32_f16(qa, kb, zero, 0, 0, 0);
        }
        // softmax over 320 keys, rows q = qt*16 + gq*4 + r
        float rinv[4];
        #pragma unroll
        for (int r = 0; r < 4; ++r) {
            float mx = -3e38f;
            #pragma unroll
            for (int kt = 0; kt < 20; ++kt) {
                float t = lg[kt][r] + mb[kt * 16 + r16];
                lg[kt][r] = t;
                mx = fmaxf(mx, t);
            }
            #pragma unroll
            for (int o = 1; o < 16; o <<= 1) mx = fmaxf(mx, __shfl_xor(mx, o));
            float s = 0.0f;
            #pragma unroll
            for (int kt = 0; kt < 20; ++kt) {
                float e = __expf(lg[kt][r] - mx);
                lg[kt][r] = e;
                s += e;
            }
            #pragma unroll
            for (int o = 1; o < 16; o <<= 1) s += __shfl_xor(s, o);
            rinv[r] = 1.0f / s;
        }
        // PV via LDS round-trip for P (layout-agnostic)
        f32x4 wa[2] = {};
        #pragma unroll
        for (int kc = 0; kc < 10; ++kc) {
            int buf = kc & 1;
            #pragma unroll
            for (int t = 0; t < 2; ++t) {
                int kt = kc * 2 + t;
                #pragma unroll
                for (int r = 0; r < 4; ++r)
                    Psh[wave][buf][gq * 4 + r][t * 16 + r16] = (f16)(lg[kt][r] * rinv[r]);
            }
            asm volatile("s_waitcnt lgkmcnt(0)" ::: "memory");
            f16x8 pa = *(const f16x8*)(&Psh[wave][buf][r16][gq * 8]);
            #pragma unroll
            for (int n = 0; n < 2; ++n) {
                f16x8 vb = *(const f16x8*)(&Vt[n * 16 + r16][kc * 32 + gq * 8]);
                wa[n] = __builtin_amdgcn_mfma_f32_16x16x32_f16(pa, vb, wa[n], 0, 0, 0);
            }
        }
        // gate + store
        #pragma unroll
        for (int n = 0; n < 2; ++n) {
            #pragma unroll
            for (int r = 0; r < 4; ++r) {
                int jq = qt * 16 + gq * 4 + r;
                int dh = n * 16 + r16;
                size_t idx = base + (size_t)jq * C_DIM + dh;
                float gv = (float)g[idx];
                gwa[idx] = (f16)(gv * wa[n][r]);
            }
        }
    }
}

// ---------------- K4: output projection — round-1 structure, Wfrag B -------
// grid 400 blocks, wave w owns 64-row subtile of the block's 256 rows.
__global__ __launch_bounds__(256) void out_kernel(const f16* __restrict__ gwa,
                                                  const f16* __restrict__ Wofrag,
                                                  const float* __restrict__ bo,
                                                  const int* __restrict__ z_mask,
                                                  float* __restrict__ out) {
    int wave = threadIdx.x >> 6;
    int lane = threadIdx.x & 63;
    int gq = lane >> 4, r16 = lane & 15;
    int row0 = blockIdx.x * 256 + wave * 64;

    f32x4 acc[4][8] = {};
    #pragma unroll
    for (int ks = 0; ks < 4; ++ks) {
        f16x8 a[4];
        #pragma unroll
        for (int m = 0; m < 4; ++m)
            a[m] = *(const f16x8*)(gwa + (size_t)(row0 + m * 16 + r16) * C_DIM + ks * 32 + gq * 8);
        #pragma unroll
        for (int n = 0; n < 8; ++n) {
            f16x8 b = *(const f16x8*)(Wofrag + (ks * 8 + n) * 512 + lane * 8);
            #pragma unroll
            for (int m = 0; m < 4; ++m)
                acc[m][n] = __builtin_amdgcn_mfma_f32_16x16x32_f16(a[m], b, acc[m][n], 0, 0, 0);
        }
    }
    #pragma unroll
    for (int m = 0; m < 4; ++m) {
        #pragma unroll
        for (int rr = 0; rr < 4; ++rr) {
            int row = row0 + m * 16 + gq * 4 + rr;
            float mk = (float)z_mask[row];
            #pragma unroll
            for (int n = 0; n < 8; ++n) {
                int col = n * 16 + r16;
                out[(size_t)row * C_DIM + col] = (acc[m][n][rr] + bo[col]) * mk;
            }
        }
    }
}

extern "C" void kernel_launch(void* const* d_in, const int* in_sizes, int n_in,
                              void* d_out, int out_size, void* d_ws, size_t ws_size,
                              hipStream_t stream) {
    const float* z        = (const float*)d_in[0];
    const int*   z_mask   = (const int*)d_in[1];
    const float* ln_scale = (const float*)d_in[2];
    const float* ln_bias  = (const float*)d_in[3];
    const float* Wq       = (const float*)d_in[4];
    const float* Wk       = (const float*)d_in[5];
    const float* Wv       = (const float*)d_in[6];
    const float* Wg       = (const float*)d_in[7];
    const float* bg       = (const float*)d_in[8];
    const float* Wo       = (const float*)d_in[9];
    const float* bo       = (const float*)d_in[10];
    float* out = (float*)d_out;

    char* ws = (char*)d_ws;
    const size_t SZ = (size_t)NROWS * C_DIM * sizeof(f16);  // 26,214,400 B
    f16* zn    = (f16*)(ws);
    f16* q     = (f16*)(ws + 1 * SZ);
    f16* k     = (f16*)(ws + 2 * SZ);
    f16* v     = (f16*)(ws + 3 * SZ);
    f16* g     = (f16*)(ws + 4 * SZ);
    f16* gwa   = zn;  // zn dead after proj_kernel (round-1 aliasing)
    f16* Wfrag = (f16*)(ws + 5 * SZ);                       // 163,840 B

    prep_kernel<<<320, 256, 0, stream>>>(Wq, Wk, Wv, Wg, Wo, Wfrag);
    ln_kernel  <<<NROWS / 4, 256, 0, stream>>>(z, ln_scale, ln_bias, zn);
    proj_kernel<<<NROWS / 64, 256, 0, stream>>>(zn, Wfrag, bg, q, k, v, g);
    attn_kernel<<<I_DIM * H_DIM, 256, 0, stream>>>(q, k, v, g, z_mask, gwa);
    out_kernel <<<NROWS / 256, 256, 0, stream>>>(gwa, Wfrag + 4 * 16384, bo, z_mask, out);
}

// Round 5
// 256.825 us; speedup vs baseline: 1.1605x; 1.1605x over previous
//
#include <hip/hip_runtime.h>

typedef _Float16 f16;
typedef _Float16 f16x2 __attribute__((ext_vector_type(2)));
typedef _Float16 f16x8 __attribute__((ext_vector_type(8)));
typedef float f32x4 __attribute__((ext_vector_type(4)));

#define I_DIM 320
#define J_DIM 320
#define C_DIM 128
#define H_DIM 4
#define DH 32
#define NROWS (I_DIM * J_DIM)   // 102400

// ---------------- K0: weight prep (f32 -> f16, MFMA B-fragment order) ------
// layout: [w][ks][n][lane][j]; value = W_w[(ks*32+(lane>>4)*8+j)*128 + n*16+(lane&15)]
__global__ __launch_bounds__(256) void prep_kernel(const float* __restrict__ Wq,
                                                   const float* __restrict__ Wk,
                                                   const float* __restrict__ Wv,
                                                   const float* __restrict__ Wg,
                                                   const float* __restrict__ Wo,
                                                   f16* __restrict__ Wfrag) {
    int f = blockIdx.x * 256 + threadIdx.x;           // < 5*16384
    int j = f & 7, lane = (f >> 3) & 63, n = (f >> 9) & 7;
    int ks = (f >> 12) & 3, w = f >> 14;
    int gq = lane >> 4, r16 = lane & 15;
    const float* W = (w == 0) ? Wq : (w == 1) ? Wk : (w == 2) ? Wv : (w == 3) ? Wg : Wo;
    Wfrag[f] = (f16)W[(size_t)(ks * 32 + gq * 8 + j) * 128 + n * 16 + r16];
}

// ---------------- K1: LayerNorm (f32 -> f16) ----------------
__global__ __launch_bounds__(256) void ln_kernel(const float* __restrict__ z,
                                                 const float* __restrict__ scale,
                                                 const float* __restrict__ bias,
                                                 f16* __restrict__ zn) {
    int wave = threadIdx.x >> 6;
    int lane = threadIdx.x & 63;
    int row = blockIdx.x * 4 + wave;
    const float* zr = z + (size_t)row * C_DIM;
    float2 x = *(const float2*)(zr + lane * 2);
    float s = x.x + x.y;
    float sq = x.x * x.x + x.y * x.y;
    #pragma unroll
    for (int o = 32; o; o >>= 1) {
        s  += __shfl_xor(s, o);
        sq += __shfl_xor(sq, o);
    }
    float mu = s * (1.0f / 128.0f);
    float var = sq * (1.0f / 128.0f) - mu * mu;
    float rs = rsqrtf(var + 1e-5f);
    int c0 = lane * 2;
    float y0 = (x.x - mu) * rs * scale[c0] + bias[c0];
    float y1 = (x.y - mu) * rs * scale[c0 + 1] + bias[c0 + 1];
    f16x2 o2 = {(f16)y0, (f16)y1};
    *(f16x2*)(zn + (size_t)row * C_DIM + c0) = o2;
}

// ---------------- K2: fused QKVG projection — LDS-transposed wide stores ----
// grid: NROWS/64 blocks, 256 threads. Wave w computes zn@W_w for its 64-row tile.
// Epilogue: acc -> per-wave LDS tile -> f16x8 coalesced stores (1KB/instr).
__global__ __launch_bounds__(256) void proj_kernel(const f16* __restrict__ zn,
                                                   const f16* __restrict__ Wfrag,
                                                   const float* __restrict__ bg,
                                                   f16* __restrict__ q, f16* __restrict__ k,
                                                   f16* __restrict__ v, f16* __restrict__ g) {
    __shared__ f16 St[4][2][16][136];  // per-wave double-buffered transpose tile
    int wave = threadIdx.x >> 6;
    int lane = threadIdx.x & 63;
    int gq = lane >> 4, r16 = lane & 15;
    int row0 = blockIdx.x * 64;

    const f16* wf = Wfrag + wave * 16384;

    f32x4 acc[4][8] = {};
    #pragma unroll
    for (int ks = 0; ks < 4; ++ks) {
        f16x8 a[4];
        #pragma unroll
        for (int m = 0; m < 4; ++m)
            a[m] = *(const f16x8*)(zn + (size_t)(row0 + m * 16 + r16) * C_DIM + ks * 32 + gq * 8);
        #pragma unroll
        for (int n = 0; n < 8; ++n) {
            f16x8 b = *(const f16x8*)(wf + (ks * 8 + n) * 512 + lane * 8);
            #pragma unroll
            for (int m = 0; m < 4; ++m)
                acc[m][n] = __builtin_amdgcn_mfma_f32_16x16x32_f16(a[m], b, acc[m][n], 0, 0, 0);
        }
    }

    f16* outp = (wave == 0) ? q : (wave == 1) ? k : (wave == 2) ? v : g;
    int rrow = lane >> 4;          // read-back row within 4-row pass
    int c8 = (lane & 15) * 8;      // read-back col start (8 f16 = 16B)
    #pragma unroll
    for (int m = 0; m < 4; ++m) {
        int buf = m & 1;
        #pragma unroll
        for (int n = 0; n < 8; ++n) {
            int col = n * 16 + r16;
            #pragma unroll
            for (int rr = 0; rr < 4; ++rr) {
                float val = acc[m][n][rr];
                if (wave == 3) val = 1.0f / (1.0f + __expf(-(val + bg[col])));
                St[wave][buf][gq * 4 + rr][col] = (f16)val;
            }
        }
        asm volatile("s_waitcnt lgkmcnt(0)" ::: "memory");  // writes visible to own wave
        #pragma unroll
        for (int p = 0; p < 4; ++p) {
            f16x8 vv = *(const f16x8*)(&St[wave][buf][p * 4 + rrow][c8]);
            *(f16x8*)(outp + (size_t)(row0 + m * 16 + p * 4 + rrow) * C_DIM + c8) = vv;
        }
    }
}

// ---------------- K3: attention per (i,h) — unchanged (round 4) ----------
__global__ __launch_bounds__(256) void attn_kernel(const f16* __restrict__ q,
                                                   const f16* __restrict__ k,
                                                   const f16* __restrict__ v,
                                                   const f16* __restrict__ g,
                                                   const int* __restrict__ z_mask,
                                                   f16* __restrict__ gwa) {
    __shared__ f16 Ksh[320][40];      // padded rows: 80B stride -> 2-way banks only
    __shared__ f16 Vt[32][328];       // V transposed [dh][key], padded
    __shared__ float mb[320];
    __shared__ f16 Psh[4][2][16][40]; // per-wave, double-buffered P chunk

    int h = blockIdx.x & 3;
    int i = blockIdx.x >> 2;
    size_t base = (size_t)i * (J_DIM * C_DIM) + h * DH;

    // stage K and V^T
    for (int t = threadIdx.x; t < 320 * 4; t += 256) {
        int row = t >> 2, c8 = (t & 3) * 8;
        f16x8 kv = *(const f16x8*)(k + base + (size_t)row * C_DIM + c8);
        *(f16x8*)(&Ksh[row][c8]) = kv;
        f16x8 vv = *(const f16x8*)(v + base + (size_t)row * C_DIM + c8);
        #pragma unroll
        for (int j = 0; j < 8; ++j) Vt[c8 + j][row] = vv[j];
    }
    for (int t = threadIdx.x; t < 320; t += 256)
        mb[t] = 1e9f * ((float)z_mask[i * J_DIM + t] - 1.0f);
    __syncthreads();

    int wave = threadIdx.x >> 6;
    int lane = threadIdx.x & 63;
    int gq = lane >> 4, r16 = lane & 15;

    for (int qt = wave; qt < 20; qt += 4) {
        f16x8 qa = *(const f16x8*)(q + base + (size_t)(qt * 16 + r16) * C_DIM + gq * 8);
        f32x4 zero = {};
        f32x4 lg[20];
        #pragma unroll
        for (int kt = 0; kt < 20; ++kt) {
            f16x8 kb = *(const f16x8*)(&Ksh[kt * 16 + r16][gq * 8]);
            lg[kt] = __builtin_amdgcn_mfma_f32_16x16x32_f16(qa, kb, zero, 0, 0, 0);
        }
        // softmax over 320 keys, rows q = qt*16 + gq*4 + r
        float rinv[4];
        #pragma unroll
        for (int r = 0; r < 4; ++r) {
            float mx = -3e38f;
            #pragma unroll
            for (int kt = 0; kt < 20; ++kt) {
                float t = lg[kt][r] + mb[kt * 16 + r16];
                lg[kt][r] = t;
                mx = fmaxf(mx, t);
            }
            #pragma unroll
            for (int o = 1; o < 16; o <<= 1) mx = fmaxf(mx, __shfl_xor(mx, o));
            float s = 0.0f;
            #pragma unroll
            for (int kt = 0; kt < 20; ++kt) {
                float e = __expf(lg[kt][r] - mx);
                lg[kt][r] = e;
                s += e;
            }
            #pragma unroll
            for (int o = 1; o < 16; o <<= 1) s += __shfl_xor(s, o);
            rinv[r] = 1.0f / s;
        }
        // PV via LDS round-trip for P (layout-agnostic)
        f32x4 wa[2] = {};
        #pragma unroll
        for (int kc = 0; kc < 10; ++kc) {
            int buf = kc & 1;
            #pragma unroll
            for (int t = 0; t < 2; ++t) {
                int kt = kc * 2 + t;
                #pragma unroll
                for (int r = 0; r < 4; ++r)
                    Psh[wave][buf][gq * 4 + r][t * 16 + r16] = (f16)(lg[kt][r] * rinv[r]);
            }
            asm volatile("s_waitcnt lgkmcnt(0)" ::: "memory");
            f16x8 pa = *(const f16x8*)(&Psh[wave][buf][r16][gq * 8]);
            #pragma unroll
            for (int n = 0; n < 2; ++n) {
                f16x8 vb = *(const f16x8*)(&Vt[n * 16 + r16][kc * 32 + gq * 8]);
                wa[n] = __builtin_amdgcn_mfma_f32_16x16x32_f16(pa, vb, wa[n], 0, 0, 0);
            }
        }
        // gate + store
        #pragma unroll
        for (int n = 0; n < 2; ++n) {
            #pragma unroll
            for (int r = 0; r < 4; ++r) {
                int jq = qt * 16 + gq * 4 + r;
                int dh = n * 16 + r16;
                size_t idx = base + (size_t)jq * C_DIM + dh;
                float gv = (float)g[idx];
                gwa[idx] = (f16)(gv * wa[n][r]);
            }
        }
    }
}

// ---------------- K4: output projection — unchanged (round 4) -------------
__global__ __launch_bounds__(256) void out_kernel(const f16* __restrict__ gwa,
                                                  const f16* __restrict__ Wofrag,
                                                  const float* __restrict__ bo,
                                                  const int* __restrict__ z_mask,
                                                  float* __restrict__ out) {
    int wave = threadIdx.x >> 6;
    int lane = threadIdx.x & 63;
    int gq = lane >> 4, r16 = lane & 15;
    int row0 = blockIdx.x * 256 + wave * 64;

    f32x4 acc[4][8] = {};
    #pragma unroll
    for (int ks = 0; ks < 4; ++ks) {
        f16x8 a[4];
        #pragma unroll
        for (int m = 0; m < 4; ++m)
            a[m] = *(const f16x8*)(gwa + (size_t)(row0 + m * 16 + r16) * C_DIM + ks * 32 + gq * 8);
        #pragma unroll
        for (int n = 0; n < 8; ++n) {
            f16x8 b = *(const f16x8*)(Wofrag + (ks * 8 + n) * 512 + lane * 8);
            #pragma unroll
            for (int m = 0; m < 4; ++m)
                acc[m][n] = __builtin_amdgcn_mfma_f32_16x16x32_f16(a[m], b, acc[m][n], 0, 0, 0);
        }
    }
    #pragma unroll
    for (int m = 0; m < 4; ++m) {
        #pragma unroll
        for (int rr = 0; rr < 4; ++rr) {
            int row = row0 + m * 16 + gq * 4 + rr;
            float mk = (float)z_mask[row];
            #pragma unroll
            for (int n = 0; n < 8; ++n) {
                int col = n * 16 + r16;
                out[(size_t)row * C_DIM + col] = (acc[m][n][rr] + bo[col]) * mk;
            }
        }
    }
}

extern "C" void kernel_launch(void* const* d_in, const int* in_sizes, int n_in,
                              void* d_out, int out_size, void* d_ws, size_t ws_size,
                              hipStream_t stream) {
    const float* z        = (const float*)d_in[0];
    const int*   z_mask   = (const int*)d_in[1];
    const float* ln_scale = (const float*)d_in[2];
    const float* ln_bias  = (const float*)d_in[3];
    const float* Wq       = (const float*)d_in[4];
    const float* Wk       = (const float*)d_in[5];
    const float* Wv       = (const float*)d_in[6];
    const float* Wg       = (const float*)d_in[7];
    const float* bg       = (const float*)d_in[8];
    const float* Wo       = (const float*)d_in[9];
    const float* bo       = (const float*)d_in[10];
    float* out = (float*)d_out;

    char* ws = (char*)d_ws;
    const size_t SZ = (size_t)NROWS * C_DIM * sizeof(f16);  // 26,214,400 B
    f16* zn    = (f16*)(ws);
    f16* q     = (f16*)(ws + 1 * SZ);
    f16* k     = (f16*)(ws + 2 * SZ);
    f16* v     = (f16*)(ws + 3 * SZ);
    f16* g     = (f16*)(ws + 4 * SZ);
    f16* gwa   = zn;  // zn dead after proj_kernel
    f16* Wfrag = (f16*)(ws + 5 * SZ);                       // 163,840 B

    prep_kernel<<<320, 256, 0, stream>>>(Wq, Wk, Wv, Wg, Wo, Wfrag);
    ln_kernel  <<<NROWS / 4, 256, 0, stream>>>(z, ln_scale, ln_bias, zn);
    proj_kernel<<<NROWS / 64, 256, 0, stream>>>(zn, Wfrag, bg, q, k, v, g);
    attn_kernel<<<I_DIM * H_DIM, 256, 0, stream>>>(q, k, v, g, z_mask, gwa);
    out_kernel <<<NROWS / 256, 256, 0, stream>>>(gwa, Wfrag + 4 * 16384, bo, z_mask, out);
}

// Round 6
// 174.553 us; speedup vs baseline: 1.7075x; 1.4713x over previous
//
#include <hip/hip_runtime.h>

typedef _Float16 f16;
typedef _Float16 f16x2 __attribute__((ext_vector_type(2)));
typedef _Float16 f16x8 __attribute__((ext_vector_type(8)));
typedef float f32x4 __attribute__((ext_vector_type(4)));

#define I_DIM 320
#define J_DIM 320
#define C_DIM 128
#define NROWS (I_DIM * J_DIM)   // 102400

// ---------------- K0: weight prep (f32 -> f16, MFMA B-fragment order) ------
// layout: [w][ks][n][lane][j]; value = W_w[(ks*32+(lane>>4)*8+j)*128 + n*16+(lane&15)]
__global__ __launch_bounds__(256) void prep_kernel(const float* __restrict__ Wq,
                                                   const float* __restrict__ Wk,
                                                   const float* __restrict__ Wv,
                                                   const float* __restrict__ Wg,
                                                   const float* __restrict__ Wo,
                                                   f16* __restrict__ Wfrag) {
    int f = blockIdx.x * 256 + threadIdx.x;           // < 5*16384
    int j = f & 7, lane = (f >> 3) & 63, n = (f >> 9) & 7;
    int ks = (f >> 12) & 3, w = f >> 14;
    int gq = lane >> 4, r16 = lane & 15;
    const float* W = (w == 0) ? Wq : (w == 1) ? Wk : (w == 2) ? Wv : (w == 3) ? Wg : Wo;
    Wfrag[f] = (f16)W[(size_t)(ks * 32 + gq * 8 + j) * 128 + n * 16 + r16];
}

// ---------------- K1: LayerNorm (f32 -> f16) — unchanged ----------------
__global__ __launch_bounds__(256) void ln_kernel(const float* __restrict__ z,
                                                 const float* __restrict__ scale,
                                                 const float* __restrict__ bias,
                                                 f16* __restrict__ zn) {
    int wave = threadIdx.x >> 6;
    int lane = threadIdx.x & 63;
    int row = blockIdx.x * 4 + wave;
    const float* zr = z + (size_t)row * C_DIM;
    float2 x = *(const float2*)(zr + lane * 2);
    float s = x.x + x.y;
    float sq = x.x * x.x + x.y * x.y;
    #pragma unroll
    for (int o = 32; o; o >>= 1) {
        s  += __shfl_xor(s, o);
        sq += __shfl_xor(sq, o);
    }
    float mu = s * (1.0f / 128.0f);
    float var = sq * (1.0f / 128.0f) - mu * mu;
    float rs = rsqrtf(var + 1e-5f);
    int c0 = lane * 2;
    float y0 = (x.x - mu) * rs * scale[c0] + bias[c0];
    float y1 = (x.y - mu) * rs * scale[c0 + 1] + bias[c0 + 1];
    f16x2 o2 = {(f16)y0, (f16)y1};
    *(f16x2*)(zn + (size_t)row * C_DIM + c0) = o2;
}

// ---------------- K2: fused QKVG-projection + attention per (i,h) ----------
// grid 1280 = i*4+h, 256 threads (4 waves). q/k/v/g never touch HBM.
__global__ __launch_bounds__(256) void attn_mega(const f16* __restrict__ zn,
                                                 const f16* __restrict__ Wfrag,
                                                 const float* __restrict__ bg,
                                                 const int* __restrict__ z_mask,
                                                 f16* __restrict__ gwa) {
    __shared__ f16 Ksh[320][40];     // k-head tile  [key][dh], r1/r5-proven geometry
    __shared__ f16 Vt[32][328];      // v-head tile transposed [dh][key]
    __shared__ float mb[320];
    __shared__ f16 Pb[4][2][16][40]; // per-wave bounce (q + P chunks)

    int h = blockIdx.x & 3;
    int i = blockIdx.x >> 2;
    size_t zbase = (size_t)i * (J_DIM * C_DIM);      // zn row block
    size_t gbase = zbase + h * 32;                   // gwa head slice

    int wave = threadIdx.x >> 6;
    int lane = threadIdx.x & 63;
    int gq = lane >> 4, r16 = lane & 15;

    const f16* wfq = Wfrag;
    const f16* wfk = Wfrag + 16384;
    const f16* wfv = Wfrag + 32768;
    const f16* wfg = Wfrag + 49152;

    // Phase A: mask bias
    for (int t = threadIdx.x; t < 320; t += 256)
        mb[t] = 1e9f * ((float)z_mask[i * J_DIM + t] - 1.0f);

    // Phase B: project K and V head-slices into LDS (wave w: row-tiles w,w+4,..)
    for (int rt = wave; rt < 20; rt += 4) {
        f16x8 a[4];
        #pragma unroll
        for (int ks = 0; ks < 4; ++ks)
            a[ks] = *(const f16x8*)(zn + zbase + (size_t)(rt * 16 + r16) * C_DIM + ks * 32 + gq * 8);
        f32x4 kacc[2] = {}, vacc[2] = {};
        #pragma unroll
        for (int ks = 0; ks < 4; ++ks) {
            #pragma unroll
            for (int n = 0; n < 2; ++n) {
                f16x8 bk = *(const f16x8*)(wfk + (ks * 8 + 2 * h + n) * 512 + lane * 8);
                kacc[n] = __builtin_amdgcn_mfma_f32_16x16x32_f16(a[ks], bk, kacc[n], 0, 0, 0);
                f16x8 bv = *(const f16x8*)(wfv + (ks * 8 + 2 * h + n) * 512 + lane * 8);
                vacc[n] = __builtin_amdgcn_mfma_f32_16x16x32_f16(a[ks], bv, vacc[n], 0, 0, 0);
            }
        }
        // C/D layout: col = n*16+r16, row = rt*16 + gq*4 + rr
        #pragma unroll
        for (int n = 0; n < 2; ++n) {
            #pragma unroll
            for (int rr = 0; rr < 4; ++rr) {
                int key = rt * 16 + gq * 4 + rr;
                int dh = n * 16 + r16;
                Ksh[key][dh] = (f16)kacc[n][rr];
                Vt[dh][key]  = (f16)vacc[n][rr];
            }
        }
    }
    __syncthreads();

    // Phase D: per wave, 5 q-tiles: q-proj + g-proj -> QK^T -> softmax -> PV -> gate
    for (int qt = wave; qt < 20; qt += 4) {
        // q & g projections for rows qt*16 + r16 (A-frags from global zn, L2-hot)
        f16x8 a[4];
        #pragma unroll
        for (int ks = 0; ks < 4; ++ks)
            a[ks] = *(const f16x8*)(zn + zbase + (size_t)(qt * 16 + r16) * C_DIM + ks * 32 + gq * 8);
        f32x4 qacc[2] = {}, gacc[2] = {};
        #pragma unroll
        for (int ks = 0; ks < 4; ++ks) {
            #pragma unroll
            for (int n = 0; n < 2; ++n) {
                f16x8 bq = *(const f16x8*)(wfq + (ks * 8 + 2 * h + n) * 512 + lane * 8);
                qacc[n] = __builtin_amdgcn_mfma_f32_16x16x32_f16(a[ks], bq, qacc[n], 0, 0, 0);
                f16x8 bgf = *(const f16x8*)(wfg + (ks * 8 + 2 * h + n) * 512 + lane * 8);
                gacc[n] = __builtin_amdgcn_mfma_f32_16x16x32_f16(a[ks], bgf, gacc[n], 0, 0, 0);
            }
        }
        // bounce q through per-wave LDS: write C-layout, read A-fragment layout
        #pragma unroll
        for (int n = 0; n < 2; ++n)
            #pragma unroll
            for (int rr = 0; rr < 4; ++rr)
                Pb[wave][0][gq * 4 + rr][n * 16 + r16] = (f16)qacc[n][rr];
        asm volatile("s_waitcnt lgkmcnt(0)" ::: "memory");
        f16x8 qa = *(const f16x8*)(&Pb[wave][0][r16][gq * 8]);

        // QK^T: one MFMA per key-tile (K = dh = 32)
        f32x4 zero = {};
        f32x4 lg[20];
        #pragma unroll
        for (int kt = 0; kt < 20; ++kt) {
            f16x8 kb = *(const f16x8*)(&Ksh[kt * 16 + r16][gq * 8]);
            lg[kt] = __builtin_amdgcn_mfma_f32_16x16x32_f16(qa, kb, zero, 0, 0, 0);
        }
        // softmax over 320 keys, rows jq = qt*16 + gq*4 + r
        float rinv[4];
        #pragma unroll
        for (int r = 0; r < 4; ++r) {
            float mx = -3e38f;
            #pragma unroll
            for (int kt = 0; kt < 20; ++kt) {
                float t = lg[kt][r] + mb[kt * 16 + r16];
                lg[kt][r] = t;
                mx = fmaxf(mx, t);
            }
            #pragma unroll
            for (int o = 1; o < 16; o <<= 1) mx = fmaxf(mx, __shfl_xor(mx, o));
            float s = 0.0f;
            #pragma unroll
            for (int kt = 0; kt < 20; ++kt) {
                float e = __expf(lg[kt][r] - mx);
                lg[kt][r] = e;
                s += e;
            }
            #pragma unroll
            for (int o = 1; o < 16; o <<= 1) s += __shfl_xor(s, o);
            rinv[r] = 1.0f / s;
        }
        // PV via double-buffered LDS bounce for P
        f32x4 wa[2] = {};
        #pragma unroll
        for (int kc = 0; kc < 10; ++kc) {
            int buf = kc & 1;
            #pragma unroll
            for (int t = 0; t < 2; ++t) {
                int kt = kc * 2 + t;
                #pragma unroll
                for (int r = 0; r < 4; ++r)
                    Pb[wave][buf][gq * 4 + r][t * 16 + r16] = (f16)(lg[kt][r] * rinv[r]);
            }
            asm volatile("s_waitcnt lgkmcnt(0)" ::: "memory");
            f16x8 pa = *(const f16x8*)(&Pb[wave][buf][r16][gq * 8]);
            #pragma unroll
            for (int n = 0; n < 2; ++n) {
                f16x8 vb = *(const f16x8*)(&Vt[n * 16 + r16][kc * 32 + gq * 8]);
                wa[n] = __builtin_amdgcn_mfma_f32_16x16x32_f16(pa, vb, wa[n], 0, 0, 0);
            }
        }
        // gate in registers (gacc layout == wa layout) + store head slice
        #pragma unroll
        for (int n = 0; n < 2; ++n) {
            #pragma unroll
            for (int r = 0; r < 4; ++r) {
                int jq = qt * 16 + gq * 4 + r;
                int dh = n * 16 + r16;
                float gv = 1.0f / (1.0f + __expf(-(gacc[n][r] + bg[h * 32 + dh])));
                gwa[gbase + (size_t)jq * C_DIM + dh] = (f16)(gv * wa[n][r]);
            }
        }
    }
}

// ---------------- K4: output projection — unchanged (r4/r5-proven) ---------
__global__ __launch_bounds__(256) void out_kernel(const f16* __restrict__ gwa,
                                                  const f16* __restrict__ Wofrag,
                                                  const float* __restrict__ bo,
                                                  const int* __restrict__ z_mask,
                                                  float* __restrict__ out) {
    int wave = threadIdx.x >> 6;
    int lane = threadIdx.x & 63;
    int gq = lane >> 4, r16 = lane & 15;
    int row0 = blockIdx.x * 256 + wave * 64;

    f32x4 acc[4][8] = {};
    #pragma unroll
    for (int ks = 0; ks < 4; ++ks) {
        f16x8 a[4];
        #pragma unroll
        for (int m = 0; m < 4; ++m)
            a[m] = *(const f16x8*)(gwa + (size_t)(row0 + m * 16 + r16) * C_DIM + ks * 32 + gq * 8);
        #pragma unroll
        for (int n = 0; n < 8; ++n) {
            f16x8 b = *(const f16x8*)(Wofrag + (ks * 8 + n) * 512 + lane * 8);
            #pragma unroll
            for (int m = 0; m < 4; ++m)
                acc[m][n] = __builtin_amdgcn_mfma_f32_16x16x32_f16(a[m], b, acc[m][n], 0, 0, 0);
        }
    }
    #pragma unroll
    for (int m = 0; m < 4; ++m) {
        #pragma unroll
        for (int rr = 0; rr < 4; ++rr) {
            int row = row0 + m * 16 + gq * 4 + rr;
            float mk = (float)z_mask[row];
            #pragma unroll
            for (int n = 0; n < 8; ++n) {
                int col = n * 16 + r16;
                out[(size_t)row * C_DIM + col] = (acc[m][n][rr] + bo[col]) * mk;
            }
        }
    }
}

extern "C" void kernel_launch(void* const* d_in, const int* in_sizes, int n_in,
                              void* d_out, int out_size, void* d_ws, size_t ws_size,
                              hipStream_t stream) {
    const float* z        = (const float*)d_in[0];
    const int*   z_mask   = (const int*)d_in[1];
    const float* ln_scale = (const float*)d_in[2];
    const float* ln_bias  = (const float*)d_in[3];
    const float* Wq       = (const float*)d_in[4];
    const float* Wk       = (const float*)d_in[5];
    const float* Wv       = (const float*)d_in[6];
    const float* Wg       = (const float*)d_in[7];
    const float* bg       = (const float*)d_in[8];
    const float* Wo       = (const float*)d_in[9];
    const float* bo       = (const float*)d_in[10];
    float* out = (float*)d_out;

    char* ws = (char*)d_ws;
    const size_t SZ = (size_t)NROWS * C_DIM * sizeof(f16);  // 26,214,400 B
    f16* zn    = (f16*)(ws);           // live through attn_mega
    f16* gwa   = (f16*)(ws + 1 * SZ);  // separate: zn still read while gwa written
    f16* Wfrag = (f16*)(ws + 2 * SZ);  // 163,840 B

    prep_kernel<<<320, 256, 0, stream>>>(Wq, Wk, Wv, Wg, Wo, Wfrag);
    ln_kernel  <<<NROWS / 4, 256, 0, stream>>>(z, ln_scale, ln_bias, zn);
    attn_mega  <<<I_DIM * 4, 256, 0, stream>>>(zn, Wfrag, bg, z_mask, gwa);
    out_kernel <<<NROWS / 256, 256, 0, stream>>>(gwa, Wfrag + 4 * 16384, bo, z_mask, out);
}